// Round 3
// baseline (460.258 us; speedup 1.0000x reference)
//
#include <hip/hip_runtime.h>
#include <hip/hip_bf16.h>
#include <stdint.h>

#define B_ 8
#define T_ 1024
#define E_ 1024
#define H_ 16
#define D_ 64
#define NREL 2047  // 2T-1

using bf16 = __hip_bfloat16;
typedef __attribute__((ext_vector_type(8))) short bhalf8;   // 8 bf16 = 4 VGPRs
typedef __attribute__((ext_vector_type(4))) float f32x4;

// ---------------------------------------------------------------------------
// fp32 -> bf16 elementwise (n multiple of 8)
// ---------------------------------------------------------------------------
__global__ __launch_bounds__(256) void cvt_f32_bf16(const float* __restrict__ s,
                                                    bf16* __restrict__ d, int n) {
  const int i = (blockIdx.x * 256 + threadIdx.x) * 8;
  if (i >= n) return;
  const float4 a = *(const float4*)(s + i);
  const float4 b = *(const float4*)(s + i + 4);
  bf16 t[8];
  t[0] = __float2bfloat16(a.x); t[1] = __float2bfloat16(a.y);
  t[2] = __float2bfloat16(a.z); t[3] = __float2bfloat16(a.w);
  t[4] = __float2bfloat16(b.x); t[5] = __float2bfloat16(b.y);
  t[6] = __float2bfloat16(b.z); t[7] = __float2bfloat16(b.w);
  *(bhalf8*)(d + i) = *(const bhalf8*)t;
}

// ---------------------------------------------------------------------------
// Precompute interpolated temporal bias: db[h][r], r = (q-k)+1023 in [0,2046]
// ---------------------------------------------------------------------------
__global__ void bias_pre(const float* __restrict__ table, const float* __restrict__ offset,
                         float* __restrict__ db) {
  const int idx = blockIdx.x * 256 + threadIdx.x;
  if (idx >= NREL * H_) return;
  const int r = idx >> 4;
  const int h = idx & 15;
  const float bounded = tanhf(offset[0]) * 0.5f;
  float adj = (float)r + bounded;
  adj = fminf(fmaxf(adj, 0.f), 2046.f);
  const int lo = (int)floorf(adj);
  const int hi = (int)ceilf(adj);
  const float wgt = adj - (float)lo;
  const float v = table[lo * H_ + h] * (1.f - wgt) + table[hi * H_ + h] * wgt;
  db[h * NREL + r] = v;
}

// ---------------------------------------------------------------------------
// C = A @ W^T + bias.  A:[M,1024] bf16 row-major, W:[1024,1024] bf16 row-major
// (torch Linear weight [out,in], K-contiguous). bias fp32.
// 128x128 tile, BK=32, register staging + ds_write_b128 (m93 structure).
// SCATTER=1: write bf16 to [B,H,T,D]; SCATTER=0 & F32OUT: fp32 [M,N].
// ---------------------------------------------------------------------------
template <int SCATTER, int F32OUT>
__global__ __launch_bounds__(256) void gemm_bt(const bf16* __restrict__ A,
                                               const bf16* __restrict__ W,
                                               const float* __restrict__ bias,
                                               void* __restrict__ dst_) {
  __shared__ bf16 As[128 * 32];
  __shared__ bf16 Bs[128 * 32];
  const int tid = threadIdx.x;
  const int lane = tid & 63;
  const int w = tid >> 6;
  const int quad = lane >> 4;
  const int l15 = lane & 15;
  const int m0 = blockIdx.x * 128;
  const int n0 = blockIdx.y * 128;
  const int wm = (w >> 1) * 64;
  const int wn = (w & 1) * 64;

  const f32x4 zero4 = {0.f, 0.f, 0.f, 0.f};
  f32x4 acc[4][4];
#pragma unroll
  for (int i = 0; i < 4; ++i)
#pragma unroll
    for (int j = 0; j < 4; ++j) acc[i][j] = zero4;

  // staging: tile [128 rows][32 cols]; thread covers rows r0, r0+64, col chunk c0
  const int r0 = tid >> 2;
  const int c0 = (tid & 3) * 8;
  const bf16* Ag = A + (size_t)(m0 + r0) * E_ + c0;
  const bf16* Wg = W + (size_t)(n0 + r0) * E_ + c0;

  for (int kt = 0; kt < 32; ++kt) {
    const int kc = kt * 32;
    bhalf8 a0 = *(const bhalf8*)(Ag + kc);
    bhalf8 a1 = *(const bhalf8*)(Ag + (size_t)64 * E_ + kc);
    bhalf8 b0 = *(const bhalf8*)(Wg + kc);
    bhalf8 b1 = *(const bhalf8*)(Wg + (size_t)64 * E_ + kc);
    __syncthreads();  // previous iteration's readers done
    *(bhalf8*)(As + r0 * 32 + c0) = a0;
    *(bhalf8*)(As + (r0 + 64) * 32 + c0) = a1;
    *(bhalf8*)(Bs + r0 * 32 + c0) = b0;
    *(bhalf8*)(Bs + (r0 + 64) * 32 + c0) = b1;
    __syncthreads();

    bhalf8 af[4], bfr[4];
#pragma unroll
    for (int t = 0; t < 4; ++t) {
      af[t] = *(const bhalf8*)(As + (wm + t * 16 + l15) * 32 + quad * 8);
      bfr[t] = *(const bhalf8*)(Bs + (wn + t * 16 + l15) * 32 + quad * 8);
    }
#pragma unroll
    for (int mt = 0; mt < 4; ++mt)
#pragma unroll
      for (int nt = 0; nt < 4; ++nt)
        acc[mt][nt] = __builtin_amdgcn_mfma_f32_16x16x32_bf16(af[mt], bfr[nt], acc[mt][nt], 0, 0, 0);
  }

#pragma unroll
  for (int mt = 0; mt < 4; ++mt) {
#pragma unroll
    for (int nt = 0; nt < 4; ++nt) {
      const int n = n0 + wn + nt * 16 + l15;
      const float bv = bias[n];
#pragma unroll
      for (int r = 0; r < 4; ++r) {
        const int m = m0 + wm + mt * 16 + quad * 4 + r;  // C row = quad*4+reg
        const float v = acc[mt][nt][r] + bv;
        if (SCATTER) {
          const int bb = m >> 10, t = m & 1023, hh = n >> 6, d = n & 63;
          ((bf16*)dst_)[(((size_t)bb * H_ + hh) * T_ + t) * D_ + d] = __float2bfloat16(v);
        } else if (F32OUT) {
          ((float*)dst_)[(size_t)m * E_ + n] = v;
        } else {
          ((bf16*)dst_)[(size_t)m * E_ + n] = __float2bfloat16(v);
        }
      }
    }
  }
}

// ---------------------------------------------------------------------------
// Flash attention per (b,h): 64 Q rows / block (4 waves x 16), KV tiles of 64.
// Q,K,V in [B,H,T,D] bf16.  Writes attention output in [B,T,E] bf16 layout.
// ---------------------------------------------------------------------------
__global__ __launch_bounds__(256) void attn_kernel(const bf16* __restrict__ Q,
                                                   const bf16* __restrict__ K,
                                                   const bf16* __restrict__ V,
                                                   const float* __restrict__ db,
                                                   bf16* __restrict__ xout) {
  const int tid = threadIdx.x;
  const int lane = tid & 63;
  const int w = tid >> 6;
  const int quad = lane >> 4;
  const int l15 = lane & 15;
  const int qt = blockIdx.x;
  const int h = blockIdx.y;
  const int b = blockIdx.z;

  __shared__ bf16 Ks[64][72];      // K[kpos][d], pad 72 breaks bank conflicts
  __shared__ bf16 Vt[64][72];      // V^T: Vt[d][kpos]
  __shared__ bf16 Ps[4][16][72];   // per-wave P tile [q_local][kpos]

  const size_t bh = (((size_t)b * H_ + h) * T_) * D_;
  const bf16* Qp = Q + bh;
  const bf16* Kp = K + bh;
  const bf16* Vp = V + bh;
  const float* dbh = db + h * NREL;

  const int qbase = qt * 64 + w * 16;

  // Q A-frags, kept in regs for all KV tiles
  bhalf8 aq[2];
#pragma unroll
  for (int ks = 0; ks < 2; ++ks)
    aq[ks] = *(const bhalf8*)(Qp + (size_t)(qbase + l15) * D_ + ks * 32 + quad * 8);

  const f32x4 zero4 = {0.f, 0.f, 0.f, 0.f};
  f32x4 o[4];
#pragma unroll
  for (int nt = 0; nt < 4; ++nt) o[nt] = zero4;
  float mrow[4] = {-1e30f, -1e30f, -1e30f, -1e30f};
  float lrow[4] = {0.f, 0.f, 0.f, 0.f};

  for (int it = 0; it < 16; ++it) {
    const int kb = it * 64;
    __syncthreads();  // protect LDS from previous iteration's readers
#pragma unroll
    for (int s = 0; s < 2; ++s) {
      const int idx = tid + s * 256;
      const int row = idx >> 3, cs = (idx & 7) * 8;
      *(bhalf8*)&Ks[row][cs] = *(const bhalf8*)(Kp + (size_t)(kb + row) * D_ + cs);
      bhalf8 vv = *(const bhalf8*)(Vp + (size_t)(kb + row) * D_ + cs);
      const bf16* vp = (const bf16*)&vv;
#pragma unroll
      for (int j = 0; j < 8; ++j) Vt[cs + j][row] = vp[j];
    }
    __syncthreads();

    // S = Q K^T : 4 n-tiles x 2 k-steps
    f32x4 s4[4];
#pragma unroll
    for (int nt = 0; nt < 4; ++nt) {
      f32x4 a = zero4;
#pragma unroll
      for (int ks = 0; ks < 2; ++ks) {
        bhalf8 bk = *(const bhalf8*)&Ks[nt * 16 + l15][ks * 32 + quad * 8];
        a = __builtin_amdgcn_mfma_f32_16x16x32_bf16(aq[ks], bk, a, 0, 0, 0);
      }
      s4[nt] = a;
    }

    // scale + bias + online softmax (C-layout row = quad*4+r, col = nt*16+l15)
#pragma unroll
    for (int r = 0; r < 4; ++r) {
      const int qrow = qbase + quad * 4 + r;
      const int relbase = qrow - kb + 1023;
      float mx = -1e30f;
#pragma unroll
      for (int nt = 0; nt < 4; ++nt) {
        const float sv = s4[nt][r] * 0.125f + dbh[relbase - nt * 16 - l15];
        s4[nt][r] = sv;
        mx = fmaxf(mx, sv);
      }
      mx = fmaxf(mx, __shfl_xor(mx, 1, 64));
      mx = fmaxf(mx, __shfl_xor(mx, 2, 64));
      mx = fmaxf(mx, __shfl_xor(mx, 4, 64));
      mx = fmaxf(mx, __shfl_xor(mx, 8, 64));
      const float mnew = fmaxf(mrow[r], mx);
      float sum = 0.f;
#pragma unroll
      for (int nt = 0; nt < 4; ++nt) {
        const float p = __expf(s4[nt][r] - mnew);
        s4[nt][r] = p;
        sum += p;
      }
      sum += __shfl_xor(sum, 1, 64);
      sum += __shfl_xor(sum, 2, 64);
      sum += __shfl_xor(sum, 4, 64);
      sum += __shfl_xor(sum, 8, 64);
      const float alpha = __expf(mrow[r] - mnew);
      lrow[r] = lrow[r] * alpha + sum;
      mrow[r] = mnew;
#pragma unroll
      for (int nt = 0; nt < 4; ++nt) o[nt][r] *= alpha;
    }

    // P: C-layout regs -> LDS (per-wave region; within-wave RAW handled by
    // compiler-inserted lgkmcnt waits)
#pragma unroll
    for (int nt = 0; nt < 4; ++nt)
#pragma unroll
      for (int r = 0; r < 4; ++r)
        Ps[w][quad * 4 + r][nt * 16 + l15] = __float2bfloat16(s4[nt][r]);

    // P A-frags + V^T B-frags -> O += P @ V
    bhalf8 pa[2];
#pragma unroll
    for (int ks = 0; ks < 2; ++ks)
      pa[ks] = *(const bhalf8*)&Ps[w][l15][ks * 32 + quad * 8];
#pragma unroll
    for (int nt = 0; nt < 4; ++nt) {
#pragma unroll
      for (int ks = 0; ks < 2; ++ks) {
        bhalf8 vb = *(const bhalf8*)&Vt[nt * 16 + l15][ks * 32 + quad * 8];
        o[nt] = __builtin_amdgcn_mfma_f32_16x16x32_bf16(pa[ks], vb, o[nt], 0, 0, 0);
      }
    }
  }

  // epilogue: O / l, store to [B,T,E] bf16
#pragma unroll
  for (int nt = 0; nt < 4; ++nt) {
#pragma unroll
    for (int r = 0; r < 4; ++r) {
      const int qrow = qbase + quad * 4 + r;
      xout[((size_t)b * T_ + qrow) * E_ + h * D_ + nt * 16 + l15] =
          __float2bfloat16(o[nt][r] / lrow[r]);
    }
  }
}

// ---------------------------------------------------------------------------
extern "C" void kernel_launch(void* const* d_in, const int* in_sizes, int n_in,
                              void* d_out, int out_size, void* d_ws, size_t ws_size,
                              hipStream_t stream) {
  const float* query = (const float*)d_in[0];
  const float* key_  = (const float*)d_in[1];
  const float* value = (const float*)d_in[2];
  const float* Wq = (const float*)d_in[3];
  const float* bq = (const float*)d_in[4];
  const float* Wk = (const float*)d_in[5];
  const float* bk = (const float*)d_in[6];
  const float* Wv = (const float*)d_in[7];
  const float* bv = (const float*)d_in[8];
  const float* Wo = (const float*)d_in[9];
  const float* bo = (const float*)d_in[10];
  const float* table = (const float*)d_in[11];
  const float* offset = (const float*)d_in[12];
  float* out = (float*)d_out;

  char* ws = (char*)d_ws;
  const size_t ME = (size_t)B_ * T_ * E_;   // 8.4M elems
  const size_t EE = (size_t)E_ * E_;        // 1M elems
  float* db = (float*)ws;                   // 131008 B, round to 131072
  bf16* xc  = (bf16*)(ws + 131072);         // converted activation input, 16 MB
  bf16* wc  = xc + ME;                      // converted Wq..Wo, 4 x 2 MB
  bf16* qb  = wc + 4 * EE;                  // [B,H,T,D] 16 MB
  bf16* kb  = qb + ME;
  bf16* vb2 = kb + ME;
  bf16* x2  = vb2 + ME;                     // attn out [B,T,E] 16 MB
  // total ws: ~88.2 MB

  dim3 bb(256, 1, 1);
  dim3 gg(64, 8, 1);
  const int gME = (int)(ME / 8 / 256);      // 4096 blocks
  const int gEE = (int)(EE / 8 / 256);      // 512 blocks

  bias_pre<<<dim3(128), bb, 0, stream>>>(table, offset, db);

  // weights once
  cvt_f32_bf16<<<dim3(gEE), bb, 0, stream>>>(Wq, wc + 0 * EE, (int)EE);
  cvt_f32_bf16<<<dim3(gEE), bb, 0, stream>>>(Wk, wc + 1 * EE, (int)EE);
  cvt_f32_bf16<<<dim3(gEE), bb, 0, stream>>>(Wv, wc + 2 * EE, (int)EE);
  cvt_f32_bf16<<<dim3(gEE), bb, 0, stream>>>(Wo, wc + 3 * EE, (int)EE);

  // Q/K/V projections (reuse xc sequentially; stream-ordered)
  cvt_f32_bf16<<<dim3(gME), bb, 0, stream>>>(query, xc, (int)ME);
  gemm_bt<1, 0><<<gg, bb, 0, stream>>>(xc, wc + 0 * EE, bq, qb);
  cvt_f32_bf16<<<dim3(gME), bb, 0, stream>>>(key_, xc, (int)ME);
  gemm_bt<1, 0><<<gg, bb, 0, stream>>>(xc, wc + 1 * EE, bk, kb);
  cvt_f32_bf16<<<dim3(gME), bb, 0, stream>>>(value, xc, (int)ME);
  gemm_bt<1, 0><<<gg, bb, 0, stream>>>(xc, wc + 2 * EE, bv, vb2);

  attn_kernel<<<dim3(16, 16, 8), bb, 0, stream>>>(qb, kb, vb2, db, x2);

  gemm_bt<0, 1><<<gg, bb, 0, stream>>>(x2, wc + 3 * EE, bo, out);
}

// Round 4
// 402.486 us; speedup vs baseline: 1.1435x; 1.1435x over previous
//
#include <hip/hip_runtime.h>
#include <hip/hip_bf16.h>
#include <stdint.h>

#define B_ 8
#define T_ 1024
#define E_ 1024
#define H_ 16
#define D_ 64
#define NREL 2047  // 2T-1

using bf16 = __hip_bfloat16;
typedef __attribute__((ext_vector_type(8))) short bhalf8;   // 8 bf16 = 4 VGPRs
typedef __attribute__((ext_vector_type(4))) float f32x4;

// --- async global->LDS, 16B/lane. LDS dest = wave-uniform base + lane*16. ---
// Direct C-style casts -> clang addrspacecast (NOT uintptr_t reinterpret).
typedef __attribute__((address_space(3))) uint32_t lds32_t;
typedef const __attribute__((address_space(1))) uint32_t glb32_t;
__device__ __forceinline__ void gld_lds16(const bf16* g, bf16* l) {
  __builtin_amdgcn_global_load_lds((glb32_t*)(const void*)g, (lds32_t*)(void*)l, 16, 0, 0);
}

// ---------------------------------------------------------------------------
// fp32 -> bf16 elementwise (n multiple of 8)
// ---------------------------------------------------------------------------
__global__ __launch_bounds__(256) void cvt_f32_bf16(const float* __restrict__ s,
                                                    bf16* __restrict__ d, int n) {
  const int i = (blockIdx.x * 256 + threadIdx.x) * 8;
  if (i >= n) return;
  const float4 a = *(const float4*)(s + i);
  const float4 b = *(const float4*)(s + i + 4);
  bf16 t[8];
  t[0] = __float2bfloat16(a.x); t[1] = __float2bfloat16(a.y);
  t[2] = __float2bfloat16(a.z); t[3] = __float2bfloat16(a.w);
  t[4] = __float2bfloat16(b.x); t[5] = __float2bfloat16(b.y);
  t[6] = __float2bfloat16(b.z); t[7] = __float2bfloat16(b.w);
  *(bhalf8*)(d + i) = *(const bhalf8*)t;
}

// ---------------------------------------------------------------------------
// Precompute interpolated temporal bias: db[h][r], r = (q-k)+1023 in [0,2046]
// ---------------------------------------------------------------------------
__global__ void bias_pre(const float* __restrict__ table, const float* __restrict__ offset,
                         float* __restrict__ db) {
  const int idx = blockIdx.x * 256 + threadIdx.x;
  if (idx >= NREL * H_) return;
  const int r = idx >> 4;
  const int h = idx & 15;
  const float bounded = tanhf(offset[0]) * 0.5f;
  float adj = (float)r + bounded;
  adj = fminf(fmaxf(adj, 0.f), 2046.f);
  const int lo = (int)floorf(adj);
  const int hi = (int)ceilf(adj);
  const float wgt = adj - (float)lo;
  const float v = table[lo * H_ + h] * (1.f - wgt) + table[hi * H_ + h] * wgt;
  db[h * NREL + r] = v;
}

// ---------------------------------------------------------------------------
// C = A @ W^T + bias.  m97 structure: 128x128 tile, BK=32,
// global_load_lds width=16 staging, 4 waves 2x2, 16x16x32 bf16 MFMA.
// SCATTER=1: write bf16 to [B,H,T,D]; else F32OUT: fp32 [M,N].
// ---------------------------------------------------------------------------
template <int SCATTER, int F32OUT>
__global__ __launch_bounds__(256) void gemm_bt(const bf16* __restrict__ A,
                                               const bf16* __restrict__ W,
                                               const float* __restrict__ bias,
                                               void* __restrict__ dst_) {
  __shared__ bf16 As[128 * 32];
  __shared__ bf16 Bs[128 * 32];
  const int tid = threadIdx.x;
  const int lane = tid & 63;
  const int w = tid >> 6;
  const int quad = lane >> 4;
  const int l15 = lane & 15;
  const int m0 = blockIdx.x * 128;
  const int n0 = blockIdx.y * 128;
  const int wm = (w >> 1) * 64;
  const int wn = (w & 1) * 64;

  const f32x4 zero4 = {0.f, 0.f, 0.f, 0.f};
  f32x4 acc[4][4];
#pragma unroll
  for (int i = 0; i < 4; ++i)
#pragma unroll
    for (int j = 0; j < 4; ++j) acc[i][j] = zero4;

  // staging: wave w fills LDS chunks 2w, 2w+1 (each 16 rows x 32 cols = 512
  // elems, LDS-linear). lane l -> row l>>2, col (l&3)*8 within chunk.
  const int srow0 = w * 32 + (lane >> 2);
  const int scol = (lane & 3) * 8;
  const bf16* Ag = A + (size_t)(m0 + srow0) * E_ + scol;
  const bf16* Wg = W + (size_t)(n0 + srow0) * E_ + scol;
  bf16* As0 = As + w * 1024 + lane * 8;
  bf16* Bs0 = Bs + w * 1024 + lane * 8;

  for (int kt = 0; kt < 32; ++kt) {
    __syncthreads();  // previous iteration's readers done
    const int kc = kt * 32;
    gld_lds16(Ag + kc, As0);
    gld_lds16(Ag + (size_t)16 * E_ + kc, As0 + 512);
    gld_lds16(Wg + kc, Bs0);
    gld_lds16(Wg + (size_t)16 * E_ + kc, Bs0 + 512);
    __syncthreads();  // forces vmcnt(0): LDS ready

    bhalf8 af[4], bfr[4];
#pragma unroll
    for (int t = 0; t < 4; ++t) {
      af[t] = *(const bhalf8*)(As + (wm + t * 16 + l15) * 32 + quad * 8);
      bfr[t] = *(const bhalf8*)(Bs + (wn + t * 16 + l15) * 32 + quad * 8);
    }
#pragma unroll
    for (int mt = 0; mt < 4; ++mt)
#pragma unroll
      for (int nt = 0; nt < 4; ++nt)
        acc[mt][nt] = __builtin_amdgcn_mfma_f32_16x16x32_bf16(af[mt], bfr[nt], acc[mt][nt], 0, 0, 0);
  }

#pragma unroll
  for (int mt = 0; mt < 4; ++mt) {
#pragma unroll
    for (int nt = 0; nt < 4; ++nt) {
      const int n = n0 + wn + nt * 16 + l15;
      const float bv = bias[n];
#pragma unroll
      for (int r = 0; r < 4; ++r) {
        const int m = m0 + wm + mt * 16 + quad * 4 + r;  // C row = quad*4+reg
        const float v = acc[mt][nt][r] + bv;
        if (SCATTER) {
          const int bb = m >> 10, t = m & 1023, hh = n >> 6, d = n & 63;
          ((bf16*)dst_)[(((size_t)bb * H_ + hh) * T_ + t) * D_ + d] = __float2bfloat16(v);
        } else if (F32OUT) {
          ((float*)dst_)[(size_t)m * E_ + n] = v;
        } else {
          ((bf16*)dst_)[(size_t)m * E_ + n] = __float2bfloat16(v);
        }
      }
    }
  }
}

// ---------------------------------------------------------------------------
// Flash attention. Q-tile 128 (4 waves x 32 rows), KV tiles of 64.
// grid: x = b*16+h (XCD locality: all q-tiles of one (b,h) share x%8),
//       y = q-tile.
// Vt uses rotated layout: row d holds kv at col (kv + 8*(d>>3)) & 63
// -> conflict-free scalar transpose writes, group-contiguous b128 reads.
// ---------------------------------------------------------------------------
__global__ __launch_bounds__(256) void attn_kernel(const bf16* __restrict__ Q,
                                                   const bf16* __restrict__ K,
                                                   const bf16* __restrict__ V,
                                                   const float* __restrict__ db,
                                                   bf16* __restrict__ xout) {
  const int tid = threadIdx.x;
  const int lane = tid & 63;
  const int w = tid >> 6;
  const int quad = lane >> 4;
  const int l15 = lane & 15;
  const int bh = blockIdx.x;          // b*16 + h
  const int h = bh & 15;
  const int b = bh >> 4;
  const int q0 = blockIdx.y * 128;

  __shared__ bf16 Ks[64][72];         // K[kv][d], pad 72
  __shared__ bf16 Vt[64][72];         // rotated V^T
  __shared__ bf16 Ps[4][32][72];      // per-wave P tiles
  __shared__ float dbs[1152];         // bias slice: dbs[i] = db[h][q0+i]

  const size_t base = (size_t)bh * T_ * D_;
  const bf16* Qp = Q + base;
  const bf16* Kp = K + base;
  const bf16* Vp = V + base;
  const float* dbh = db + h * NREL;

  // preload bias slice (rel = q-kv+1023 in [q0, q0+1150])
  for (int t = tid; t < 1151; t += 256) dbs[t] = dbh[q0 + t];

  const int qw = q0 + w * 32;
  // Q A-frags for 2 m-tiles, kept in regs
  bhalf8 aq[2][2];
#pragma unroll
  for (int mt = 0; mt < 2; ++mt)
#pragma unroll
    for (int ks = 0; ks < 2; ++ks)
      aq[mt][ks] = *(const bhalf8*)(Qp + (size_t)(qw + mt * 16 + l15) * D_ + ks * 32 + quad * 8);

  const f32x4 zero4 = {0.f, 0.f, 0.f, 0.f};
  f32x4 o[2][4];
  float mrow[2][4], lrow[2][4];
#pragma unroll
  for (int mt = 0; mt < 2; ++mt)
#pragma unroll
    for (int nt = 0; nt < 4; ++nt) {
      o[mt][nt] = zero4;
      mrow[mt][nt] = -1e30f;  // reuse [4] for r
      lrow[mt][nt] = 0.f;
    }

  for (int it = 0; it < 16; ++it) {
    const int kb = it * 64;
    __syncthreads();
    // stage K (natural) + V (rotated transpose). 2 chunks/thread.
#pragma unroll
    for (int s = 0; s < 2; ++s) {
      const int idx = tid + s * 256;
      const int row = idx >> 3;              // kv local 0..63
      const int c8 = (idx & 7) * 8;          // d chunk
      *(bhalf8*)&Ks[row][c8] = *(const bhalf8*)(Kp + (size_t)(kb + row) * D_ + c8);
      bhalf8 vv = *(const bhalf8*)(Vp + (size_t)(kb + row) * D_ + c8);
      const bf16* vp = (const bf16*)&vv;
      const int kvp = (row + c8) & 63;       // rotation: kv + 8*(d>>3), d>>3=c8/8
#pragma unroll
      for (int j = 0; j < 8; ++j) Vt[c8 + j][kvp] = vp[j];
    }
    __syncthreads();

    // S = Q K^T
    f32x4 s4[2][4];
#pragma unroll
    for (int nt = 0; nt < 4; ++nt) {
      const bhalf8 bk0 = *(const bhalf8*)&Ks[nt * 16 + l15][quad * 8];
      const bhalf8 bk1 = *(const bhalf8*)&Ks[nt * 16 + l15][32 + quad * 8];
#pragma unroll
      for (int mt = 0; mt < 2; ++mt) {
        f32x4 a = zero4;
        a = __builtin_amdgcn_mfma_f32_16x16x32_bf16(aq[mt][0], bk0, a, 0, 0, 0);
        a = __builtin_amdgcn_mfma_f32_16x16x32_bf16(aq[mt][1], bk1, a, 0, 0, 0);
        s4[mt][nt] = a;
      }
    }

    // scale + bias + online softmax (C row = quad*4+r, col = nt*16+l15)
#pragma unroll
    for (int mt = 0; mt < 2; ++mt) {
#pragma unroll
      for (int r = 0; r < 4; ++r) {
        const int ql = w * 32 + mt * 16 + quad * 4 + r;
        const int ib = ql - kb + 1023;       // dbs idx for nt=0,l15=0
        float mx = -1e30f;
#pragma unroll
        for (int nt = 0; nt < 4; ++nt) {
          const float sv = s4[mt][nt][r] * 0.125f + dbs[ib - nt * 16 - l15];
          s4[mt][nt][r] = sv;
          mx = fmaxf(mx, sv);
        }
        mx = fmaxf(mx, __shfl_xor(mx, 1, 64));
        mx = fmaxf(mx, __shfl_xor(mx, 2, 64));
        mx = fmaxf(mx, __shfl_xor(mx, 4, 64));
        mx = fmaxf(mx, __shfl_xor(mx, 8, 64));
        const float mnew = fmaxf(mrow[mt][r], mx);
        float sum = 0.f;
#pragma unroll
        for (int nt = 0; nt < 4; ++nt) {
          const float p = __expf(s4[mt][nt][r] - mnew);
          s4[mt][nt][r] = p;
          sum += p;
        }
        sum += __shfl_xor(sum, 1, 64);
        sum += __shfl_xor(sum, 2, 64);
        sum += __shfl_xor(sum, 4, 64);
        sum += __shfl_xor(sum, 8, 64);
        const float alpha = __expf(mrow[mt][r] - mnew);
        lrow[mt][r] = lrow[mt][r] * alpha + sum;
        mrow[mt][r] = mnew;
#pragma unroll
        for (int nt = 0; nt < 4; ++nt) o[mt][nt][r] *= alpha;
      }
    }

    // P: C-layout regs -> per-wave LDS
#pragma unroll
    for (int mt = 0; mt < 2; ++mt)
#pragma unroll
      for (int nt = 0; nt < 4; ++nt)
#pragma unroll
        for (int r = 0; r < 4; ++r)
          Ps[w][mt * 16 + quad * 4 + r][nt * 16 + l15] = __float2bfloat16(s4[mt][nt][r]);

    // P A-frags + rotated-V^T B-frags -> O += P @ V
    bhalf8 pa[2][2];
#pragma unroll
    for (int mt = 0; mt < 2; ++mt)
#pragma unroll
      for (int ks = 0; ks < 2; ++ks)
        pa[mt][ks] = *(const bhalf8*)&Ps[w][mt * 16 + l15][ks * 32 + quad * 8];
    const int rot = (l15 >> 3);  // d>>3 = 2*nt + (l15>>3)
#pragma unroll
    for (int nt = 0; nt < 4; ++nt) {
      const int drow = nt * 16 + l15;
#pragma unroll
      for (int ks = 0; ks < 2; ++ks) {
        const int gp = (4 * ks + quad + 2 * nt + rot) & 7;
        const bhalf8 vb = *(const bhalf8*)&Vt[drow][gp * 8];
#pragma unroll
        for (int mt = 0; mt < 2; ++mt)
          o[mt][nt] = __builtin_amdgcn_mfma_f32_16x16x32_bf16(pa[mt][ks], vb, o[mt][nt], 0, 0, 0);
      }
    }
  }

  // epilogue: O / l -> [B,T,E] bf16
#pragma unroll
  for (int mt = 0; mt < 2; ++mt) {
#pragma unroll
    for (int nt = 0; nt < 4; ++nt) {
#pragma unroll
      for (int r = 0; r < 4; ++r) {
        const int qrow = qw + mt * 16 + quad * 4 + r;
        xout[((size_t)b * T_ + qrow) * E_ + h * D_ + nt * 16 + l15] =
            __float2bfloat16(o[mt][nt][r] / lrow[mt][r]);
      }
    }
  }
}

// ---------------------------------------------------------------------------
extern "C" void kernel_launch(void* const* d_in, const int* in_sizes, int n_in,
                              void* d_out, int out_size, void* d_ws, size_t ws_size,
                              hipStream_t stream) {
  const float* query = (const float*)d_in[0];
  const float* key_  = (const float*)d_in[1];
  const float* value = (const float*)d_in[2];
  const float* Wq = (const float*)d_in[3];
  const float* bq = (const float*)d_in[4];
  const float* Wk = (const float*)d_in[5];
  const float* bk = (const float*)d_in[6];
  const float* Wv = (const float*)d_in[7];
  const float* bv = (const float*)d_in[8];
  const float* Wo = (const float*)d_in[9];
  const float* bo = (const float*)d_in[10];
  const float* table = (const float*)d_in[11];
  const float* offset = (const float*)d_in[12];
  float* out = (float*)d_out;

  char* ws = (char*)d_ws;
  const size_t ME = (size_t)B_ * T_ * E_;   // 8.4M elems
  const size_t EE = (size_t)E_ * E_;        // 1M elems
  float* db = (float*)ws;                   // 131008 B, round to 131072
  bf16* xc  = (bf16*)(ws + 131072);         // converted activation input
  bf16* wc  = xc + ME;                      // converted Wq..Wo
  bf16* qb  = wc + 4 * EE;                  // [B,H,T,D]
  bf16* kb  = qb + ME;
  bf16* vb2 = kb + ME;
  bf16* x2  = vb2 + ME;                     // attn out [B,T,E]

  dim3 bb(256, 1, 1);
  dim3 gg(64, 8, 1);
  const int gME = (int)(ME / 8 / 256);
  const int gEE = (int)(EE / 8 / 256);

  bias_pre<<<dim3(128), bb, 0, stream>>>(table, offset, db);

  cvt_f32_bf16<<<dim3(gEE), bb, 0, stream>>>(Wq, wc + 0 * EE, (int)EE);
  cvt_f32_bf16<<<dim3(gEE), bb, 0, stream>>>(Wk, wc + 1 * EE, (int)EE);
  cvt_f32_bf16<<<dim3(gEE), bb, 0, stream>>>(Wv, wc + 2 * EE, (int)EE);
  cvt_f32_bf16<<<dim3(gEE), bb, 0, stream>>>(Wo, wc + 3 * EE, (int)EE);

  cvt_f32_bf16<<<dim3(gME), bb, 0, stream>>>(query, xc, (int)ME);
  gemm_bt<1, 0><<<gg, bb, 0, stream>>>(xc, wc + 0 * EE, bq, qb);
  cvt_f32_bf16<<<dim3(gME), bb, 0, stream>>>(key_, xc, (int)ME);
  gemm_bt<1, 0><<<gg, bb, 0, stream>>>(xc, wc + 1 * EE, bk, kb);
  cvt_f32_bf16<<<dim3(gME), bb, 0, stream>>>(value, xc, (int)ME);
  gemm_bt<1, 0><<<gg, bb, 0, stream>>>(xc, wc + 2 * EE, bv, vb2);

  attn_kernel<<<dim3(128, 8, 1), bb, 0, stream>>>(qb, kb, vb2, db, x2);

  gemm_bt<0, 1><<<gg, bb, 0, stream>>>(x2, wc + 3 * EE, bo, out);
}